// Round 1
// baseline (1221.378 us; speedup 1.0000x reference)
//
#include <hip/hip_runtime.h>
#include <stdint.h>

#define NN 100000
#define NE 3200000
#define KIN 512
#define HID 256
#define NOUT 40

typedef __attribute__((ext_vector_type(8))) __bf16 bf16x8;
typedef __attribute__((ext_vector_type(4))) float f32x4;

__device__ __forceinline__ float b2f(unsigned short u) {
  union { unsigned int i; float f; } x; x.i = ((unsigned int)u) << 16; return x.f;
}
__device__ __forceinline__ unsigned short f2b(float f) {
  unsigned int i = __float_as_uint(f);
  return (unsigned short)((i + 0x7FFFu + ((i >> 16) & 1u)) >> 16);
}
// XOR-swizzled LDS address for [row][32] bf16 tiles (row stride 64B).
__device__ __forceinline__ unsigned short* swz(unsigned short* base, int row, int kk) {
  int byte = (row * 64 + kk * 2) ^ ((row & 7) << 4);
  return (unsigned short*)((char*)base + byte);
}

// ---------------- CSR build ----------------
__global__ void k_degree(const int* __restrict__ col, int* __restrict__ deg) {
  int e = blockIdx.x * blockDim.x + threadIdx.x;
  if (e < NE) atomicAdd(&deg[col[e]], 1);
}

__global__ void k_dn(const int* __restrict__ deg, float* __restrict__ dn) {
  int i = blockIdx.x * blockDim.x + threadIdx.x;
  if (i < NN) { int d = deg[i]; dn[i] = d > 0 ? rsqrtf((float)d) : 0.f; }
}

#define SCAN_CH 1024
__global__ void k_scan_part(const int* __restrict__ deg, int* __restrict__ partials) {
  __shared__ int lds[4];
  int b = blockIdx.x, t = threadIdx.x;
  int base = b * SCAN_CH;
  int s = 0;
  for (int j = 0; j < 4; ++j) { int i = base + t + 256 * j; if (i < NN) s += deg[i]; }
  for (int d = 32; d > 0; d >>= 1) s += __shfl_down(s, d, 64);
  int lane = t & 63, w = t >> 6;
  if (lane == 0) lds[w] = s;
  __syncthreads();
  if (t == 0) partials[b] = lds[0] + lds[1] + lds[2] + lds[3];
}

__global__ void k_scan_partials(int* __restrict__ partials, int nb) {
  __shared__ int lds[2];
  int t = threadIdx.x;  // 128 threads, nb <= 128
  int v = (t < nb) ? partials[t] : 0;
  int lane = t & 63, w = t >> 6;
  int s = v;
  for (int d = 1; d < 64; d <<= 1) { int o = __shfl_up(s, d, 64); if (lane >= d) s += o; }
  if (lane == 63) lds[w] = s;
  __syncthreads();
  int base = (w == 1) ? lds[0] : 0;
  if (t < nb) partials[t] = base + s - v;  // exclusive
}

__global__ void k_scan_final(const int* __restrict__ deg, const int* __restrict__ partials,
                             int* __restrict__ colptr, int* __restrict__ pos) {
  __shared__ int lds[4];
  int b = blockIdx.x, t = threadIdx.x;
  int base = b * SCAN_CH + t * 4;
  int d0 = (base + 0 < NN) ? deg[base + 0] : 0;
  int d1 = (base + 1 < NN) ? deg[base + 1] : 0;
  int d2 = (base + 2 < NN) ? deg[base + 2] : 0;
  int d3 = (base + 3 < NN) ? deg[base + 3] : 0;
  int tot = d0 + d1 + d2 + d3;
  int lane = t & 63, w = t >> 6;
  int s = tot;
  for (int d = 1; d < 64; d <<= 1) { int o = __shfl_up(s, d, 64); if (lane >= d) s += o; }
  if (lane == 63) lds[w] = s;
  __syncthreads();
  int wbase = 0;
  for (int i = 0; i < 4; ++i) wbase += (i < w) ? lds[i] : 0;
  int excl = wbase + s - tot + partials[b];
  int p0 = excl, p1 = p0 + d0, p2 = p1 + d1, p3 = p2 + d2, p4 = p3 + d3;
  if (base + 0 <= NN) colptr[base + 0] = p0;
  if (base + 1 <= NN) colptr[base + 1] = p1;
  if (base + 2 <= NN) colptr[base + 2] = p2;
  if (base + 3 <= NN) colptr[base + 3] = p3;
  if (base + 4 == NN) colptr[NN] = p4;  // covered anyway by next thread except the very end
  if (base + 0 < NN) pos[base + 0] = p0;
  if (base + 1 < NN) pos[base + 1] = p1;
  if (base + 2 < NN) pos[base + 2] = p2;
  if (base + 3 < NN) pos[base + 3] = p3;
}

__global__ void k_csr_fill(const int* __restrict__ row, const int* __restrict__ col,
                           int* __restrict__ pos, int* __restrict__ csr_row) {
  int e = blockIdx.x * blockDim.x + threadIdx.x;
  if (e < NE) {
    int c = col[e];
    int p = atomicAdd(&pos[c], 1);
    csr_row[p] = row[e];
  }
}

// ---------------- weight prep: transpose to [n][k] bf16, fold BN+bias ----------------
__global__ void k_prep(const float* __restrict__ fc0_W, const float* __restrict__ fc0_b,
                       const float* __restrict__ conv_W, const float* __restrict__ conv_b,
                       const float* __restrict__ bn_gamma, const float* __restrict__ bn_beta,
                       const float* __restrict__ bn_mean, const float* __restrict__ bn_var,
                       const float* __restrict__ clf_W,
                       unsigned short* __restrict__ W0t, unsigned short* __restrict__ Wct,
                       unsigned short* __restrict__ Wclft,
                       float* __restrict__ epia, float* __restrict__ epib) {
  int idx = blockIdx.x * 256 + threadIdx.x;
  if (idx < 131072) {                       // W0t[n*512+k] = fc0_W[k][n]
    int n = idx >> 9, k = idx & 511;
    W0t[idx] = f2b(fc0_W[k * 256 + n]);
  } else if (idx < 262144) {                // Wct[l][n*256+k] = conv_W[l][k][n]
    int j = idx - 131072;
    int l = j >> 16, rem = j & 65535, n = rem >> 8, k = rem & 255;
    Wct[j] = f2b(conv_W[l * 65536 + k * 256 + n]);
  } else if (idx < 262144 + 48 * 256) {     // Wclft[n*256+k], rows 40..47 zero
    int j = idx - 262144;
    int n = j >> 8, k = j & 255;
    Wclft[j] = f2b(n < NOUT ? clf_W[k * NOUT + n] : 0.f);
  } else if (idx < 262144 + 12288 + 768) {  // epilogue constants per BN layer
    int j = idx - 262144 - 12288;           // layer*256 + c
    int layer = j >> 8, c = j & 255;
    float a = bn_gamma[j] * rsqrtf(bn_var[j] + 1e-5f);
    float bias = (layer == 0) ? fc0_b[c] : conv_b[(layer - 1) * 256 + c];
    epia[j] = a;
    epib[j] = bn_beta[j] + (bias - bn_mean[j]) * a;
  }
}

// ---------------- MFMA GEMM: [NN x K] * [K x BN] with fused epilogue ----------------
// EPI 0: y=relu(a*acc+b) -> bf16     EPI 1: +prev residual -> bf16     EPI 2: acc+clf_b -> f32 (col<40)
template <int K, int BN, bool AF32, int EPI>
__global__ __launch_bounds__(256) void k_gemm(const void* __restrict__ Av,
                                              const unsigned short* __restrict__ Bt,
                                              const float* __restrict__ epia,
                                              const float* __restrict__ epib,
                                              const unsigned short* __restrict__ prev,
                                              const float* __restrict__ clfb,
                                              void* __restrict__ outv) {
  __shared__ unsigned short ldsA[64 * 32];
  __shared__ unsigned short ldsB[BN * 32];
  const int t = threadIdx.x;
  const int w = t >> 6, lane = t & 63;
  const int lo = lane & 15, hi = lane >> 4;
  const int m0 = blockIdx.x * 64;
  constexpr int NF = BN / 16;
  f32x4 acc[NF];
#pragma unroll
  for (int f = 0; f < NF; ++f) acc[f] = (f32x4){0.f, 0.f, 0.f, 0.f};

  const int arow = t >> 2;       // 0..63
  const int akk = (t & 3) * 8;   // element offset in K-step
  const int rg = m0 + arow;

  for (int k0 = 0; k0 < K; k0 += 32) {
    // stage A
    if (AF32) {
      const float* A = (const float*)Av;
      float4 v0 = {0.f, 0.f, 0.f, 0.f}, v1 = {0.f, 0.f, 0.f, 0.f};
      if (rg < NN) {
        v0 = *(const float4*)(A + (size_t)rg * K + k0 + akk);
        v1 = *(const float4*)(A + (size_t)rg * K + k0 + akk + 4);
      }
      union { unsigned short u[8]; int4 v; } pk;
      pk.u[0] = f2b(v0.x); pk.u[1] = f2b(v0.y); pk.u[2] = f2b(v0.z); pk.u[3] = f2b(v0.w);
      pk.u[4] = f2b(v1.x); pk.u[5] = f2b(v1.y); pk.u[6] = f2b(v1.z); pk.u[7] = f2b(v1.w);
      *(int4*)(void*)swz(ldsA, arow, akk) = pk.v;
    } else {
      const unsigned short* A = (const unsigned short*)Av;
      int4 v = {0, 0, 0, 0};
      if (rg < NN) v = *(const int4*)(A + (size_t)rg * K + k0 + akk);
      *(int4*)(void*)swz(ldsA, arow, akk) = v;
    }
    // stage B (Bt is [BN][K] bf16, row-major)
    if (BN == 256) {
#pragma unroll
      for (int j = 0; j < 4; ++j) {
        int n = (t >> 2) + 64 * j;
        int4 v = *(const int4*)(Bt + (size_t)n * K + k0 + akk);
        *(int4*)(void*)swz(ldsB, n, akk) = v;
      }
    } else {
      if (t < BN * 4) {
        int n = t >> 2;
        int4 v = *(const int4*)(Bt + (size_t)n * K + k0 + akk);
        *(int4*)(void*)swz(ldsB, n, akk) = v;
      }
    }
    __syncthreads();
    bf16x8 af = *(const bf16x8*)(void*)swz(ldsA, w * 16 + lo, hi * 8);
#pragma unroll
    for (int f = 0; f < NF; ++f) {
      bf16x8 bf = *(const bf16x8*)(void*)swz(ldsB, f * 16 + lo, hi * 8);
      acc[f] = __builtin_amdgcn_mfma_f32_16x16x32_bf16(af, bf, acc[f], 0, 0, 0);
    }
    __syncthreads();
  }

  const int rbase = m0 + w * 16 + hi * 4;  // C/D: col=lane&15, row=(lane>>4)*4+reg
  if constexpr (EPI == 2) {
    float* out = (float*)outv;
#pragma unroll
    for (int f = 0; f < NF; ++f) {
      int c = f * 16 + lo;
      if (c >= NOUT) continue;
      float bb = clfb[c];
#pragma unroll
      for (int j = 0; j < 4; ++j) {
        int r = rbase + j;
        if (r < NN) out[(size_t)r * NOUT + c] = acc[f][j] + bb;
      }
    }
  } else {
    unsigned short* out = (unsigned short*)outv;
#pragma unroll
    for (int f = 0; f < NF; ++f) {
      int c = f * 16 + lo;
      float a = epia[c], b = epib[c];
#pragma unroll
      for (int j = 0; j < 4; ++j) {
        int r = rbase + j;
        if (r >= NN) continue;
        float y = fmaxf(a * acc[f][j] + b, 0.f);
        if constexpr (EPI == 1) y += b2f(prev[(size_t)r * HID + c]);
        out[(size_t)r * HID + c] = f2b(y);
      }
    }
  }
}

// ---------------- aggregation: one wave per node, CSR gather ----------------
__global__ __launch_bounds__(256) void k_agg(const int* __restrict__ colptr,
                                             const int* __restrict__ csr_row,
                                             const float* __restrict__ dn,
                                             const unsigned short* __restrict__ hsrc,
                                             unsigned short* __restrict__ hdst) {
  int w = threadIdx.x >> 6, lane = threadIdx.x & 63;
  int i = blockIdx.x * 4 + w;
  if (i >= NN) return;
  int e0 = colptr[i], e1 = colptr[i + 1];
  float dni = dn[i];
  float a0 = 0.f, a1 = 0.f, a2 = 0.f, a3 = 0.f;
  int e = e0;
  for (; e + 1 < e1; e += 2) {
    int r0 = csr_row[e], r1 = csr_row[e + 1];
    float v0 = dni * dn[r0], v1 = dni * dn[r1];
    ushort4 h0 = *(const ushort4*)(hsrc + (size_t)r0 * HID + lane * 4);
    ushort4 h1 = *(const ushort4*)(hsrc + (size_t)r1 * HID + lane * 4);
    a0 += v0 * b2f(h0.x) + v1 * b2f(h1.x);
    a1 += v0 * b2f(h0.y) + v1 * b2f(h1.y);
    a2 += v0 * b2f(h0.z) + v1 * b2f(h1.z);
    a3 += v0 * b2f(h0.w) + v1 * b2f(h1.w);
  }
  if (e < e1) {
    int r0 = csr_row[e];
    float v0 = dni * dn[r0];
    ushort4 h0 = *(const ushort4*)(hsrc + (size_t)r0 * HID + lane * 4);
    a0 += v0 * b2f(h0.x); a1 += v0 * b2f(h0.y); a2 += v0 * b2f(h0.z); a3 += v0 * b2f(h0.w);
  }
  ushort4 o; o.x = f2b(a0); o.y = f2b(a1); o.z = f2b(a2); o.w = f2b(a3);
  *(ushort4*)(hdst + (size_t)i * HID + lane * 4) = o;
}

extern "C" void kernel_launch(void* const* d_in, const int* in_sizes, int n_in,
                              void* d_out, int out_size, void* d_ws, size_t ws_size,
                              hipStream_t stream) {
  const float* x        = (const float*)d_in[0];
  const int*   edge     = (const int*)d_in[1];
  const int*   erow     = edge;
  const int*   ecol     = edge + NE;
  const float* fc0_W    = (const float*)d_in[2];
  const float* fc0_b    = (const float*)d_in[3];
  const float* conv_W   = (const float*)d_in[4];
  const float* conv_b   = (const float*)d_in[5];
  const float* bn_gamma = (const float*)d_in[6];
  const float* bn_beta  = (const float*)d_in[7];
  const float* bn_mean  = (const float*)d_in[8];
  const float* bn_var   = (const float*)d_in[9];
  const float* clf_W    = (const float*)d_in[10];
  const float* clf_b    = (const float*)d_in[11];

  char* p = (char*)d_ws;
  auto alloc = [&](size_t bytes) { char* r = p; p += (bytes + 255) & ~(size_t)255; return r; };
  int*   deg      = (int*)alloc((size_t)NN * 4);
  float* dn       = (float*)alloc((size_t)NN * 4);
  int*   colptr   = (int*)alloc((size_t)(NN + 1) * 4);
  int*   pos      = (int*)alloc((size_t)NN * 4);
  int*   partials = (int*)alloc(1024);
  int*   csr_row  = (int*)alloc((size_t)NE * 4);
  unsigned short* W0t   = (unsigned short*)alloc((size_t)256 * 512 * 2);
  unsigned short* Wct   = (unsigned short*)alloc((size_t)2 * 256 * 256 * 2);
  unsigned short* Wclft = (unsigned short*)alloc((size_t)48 * 256 * 2);
  float* epia = (float*)alloc(768 * 4);
  float* epib = (float*)alloc(768 * 4);
  unsigned short* h0 = (unsigned short*)alloc((size_t)NN * HID * 2);
  unsigned short* hA = (unsigned short*)alloc((size_t)NN * HID * 2);
  unsigned short* hB = (unsigned short*)alloc((size_t)NN * HID * 2);

  hipMemsetAsync(deg, 0, (size_t)NN * 4, stream);
  k_degree<<<(NE + 255) / 256, 256, 0, stream>>>(ecol, deg);
  k_dn<<<(NN + 255) / 256, 256, 0, stream>>>(deg, dn);
  int nb = (NN + SCAN_CH - 1) / SCAN_CH;  // 98
  k_scan_part<<<nb, 256, 0, stream>>>(deg, partials);
  k_scan_partials<<<1, 128, 0, stream>>>(partials, nb);
  k_scan_final<<<nb, 256, 0, stream>>>(deg, partials, colptr, pos);
  k_csr_fill<<<(NE + 255) / 256, 256, 0, stream>>>(erow, ecol, pos, csr_row);
  k_prep<<<1075, 256, 0, stream>>>(fc0_W, fc0_b, conv_W, conv_b, bn_gamma, bn_beta,
                                   bn_mean, bn_var, clf_W, W0t, Wct, Wclft, epia, epib);

  int gm = (NN + 63) / 64;  // 1563
  // fc0 + BN0 + ReLU -> h0
  k_gemm<KIN, 256, true, 0><<<gm, 256, 0, stream>>>(x, W0t, epia, epib, nullptr, nullptr, h0);
  // layer 0
  k_agg<<<(NN + 3) / 4, 256, 0, stream>>>(colptr, csr_row, dn, h0, hA);
  k_gemm<HID, 256, false, 1><<<gm, 256, 0, stream>>>(hA, Wct, epia + 256, epib + 256, h0, nullptr, hB);
  // layer 1
  k_agg<<<(NN + 3) / 4, 256, 0, stream>>>(colptr, csr_row, dn, hB, hA);
  k_gemm<HID, 256, false, 1><<<gm, 256, 0, stream>>>(hA, Wct + 65536, epia + 512, epib + 512, h0, nullptr, hB);
  // classifier -> f32 out
  k_gemm<HID, 48, false, 2><<<gm, 256, 0, stream>>>(hB, Wclft, nullptr, nullptr, nullptr, clf_b, d_out);
}

// Round 2
// 910.292 us; speedup vs baseline: 1.3417x; 1.3417x over previous
//
#include <hip/hip_runtime.h>
#include <stdint.h>

#define NN 100000
#define NE 3200000
#define KIN 512
#define HID 256
#define NOUT 40
#define NB 256        // coarse buckets (col >> 9); 196 used
#define BSHIFT 9
#define EPB 8192      // edges per block in bucket pass

typedef __attribute__((ext_vector_type(8))) __bf16 bf16x8;
typedef __attribute__((ext_vector_type(4))) float f32x4;

__device__ __forceinline__ float b2f(unsigned short u) {
  union { unsigned int i; float f; } x; x.i = ((unsigned int)u) << 16; return x.f;
}
__device__ __forceinline__ unsigned short f2b(float f) {
  unsigned int i = __float_as_uint(f);
  return (unsigned short)((i + 0x7FFFu + ((i >> 16) & 1u)) >> 16);
}
// XOR-swizzled LDS address for [row][32] bf16 tiles (row stride 64B).
__device__ __forceinline__ unsigned short* swz(unsigned short* base, int row, int kk) {
  int byte = (row * 64 + kk * 2) ^ ((row & 7) << 4);
  return (unsigned short*)((char*)base + byte);
}

// ---------------- bucketed CSR build ----------------
// Pass 1: global bucket histogram
__global__ __launch_bounds__(256) void k_bhist(const int* __restrict__ ecol, int* __restrict__ bcnt) {
  __shared__ int hist[NB];
  int t = threadIdx.x;
  hist[t] = 0;
  __syncthreads();
  int e0 = blockIdx.x * EPB, e1 = min(e0 + EPB, NE);
  for (int e = e0 + t; e < e1; e += 256) atomicAdd(&hist[ecol[e] >> BSHIFT], 1);
  __syncthreads();
  if (hist[t]) atomicAdd(&bcnt[t], hist[t]);
}

// Pass 2: exclusive scan of 256 bucket counts -> bbase, cursor
__global__ void k_bscan(const int* __restrict__ bcnt, int* __restrict__ bbase, int* __restrict__ cursor) {
  __shared__ int wsum[4];
  int t = threadIdx.x, lane = t & 63, w = t >> 6;
  int v = bcnt[t];
  int s = v;
  for (int d = 1; d < 64; d <<= 1) { int o = __shfl_up(s, d, 64); if (lane >= d) s += o; }
  if (lane == 63) wsum[w] = s;
  __syncthreads();
  int add = 0;
  for (int i = 0; i < 4; ++i) add += (i < w) ? wsum[i] : 0;
  int excl = add + s - v;
  bbase[t] = excl;
  cursor[t] = excl;
}

// Pass 3: place edges into bucketed buffer (packed col<<32|row), block-contiguous runs
__global__ __launch_bounds__(256) void k_bucket(const int* __restrict__ erow, const int* __restrict__ ecol,
                                                int* __restrict__ cursor, long long* __restrict__ ebuf) {
  __shared__ int hist[NB];
  __shared__ int base[NB];
  int t = threadIdx.x;
  hist[t] = 0;
  __syncthreads();
  int e0 = blockIdx.x * EPB, e1 = min(e0 + EPB, NE);
  for (int e = e0 + t; e < e1; e += 256) atomicAdd(&hist[ecol[e] >> BSHIFT], 1);
  __syncthreads();
  int c = hist[t];
  int myb = (c > 0) ? atomicAdd(&cursor[t], c) : 0;
  base[t] = myb;
  hist[t] = 0;  // reuse as local rank cursor
  __syncthreads();
  for (int e = e0 + t; e < e1; e += 256) {
    int col = ecol[e];
    int b = col >> BSHIFT;
    int r = atomicAdd(&hist[b], 1);
    ebuf[(size_t)base[b] + r] = ((long long)col << 32) | (unsigned int)erow[e];
  }
}

// Pass 4: per-bucket col-degree histogram in LDS -> deg
__global__ __launch_bounds__(256) void k_subdeg(const long long* __restrict__ ebuf,
                                                const int* __restrict__ bbase, const int* __restrict__ bcnt,
                                                int* __restrict__ deg) {
  __shared__ int h[512];
  int t = threadIdx.x, b = blockIdx.x;
  h[t] = 0; h[t + 256] = 0;
  __syncthreads();
  int s = bbase[b], e = s + bcnt[b];
  for (int i = s + t; i < e; i += 256) {
    int col = (int)(ebuf[i] >> 32);
    atomicAdd(&h[col & 511], 1);
  }
  __syncthreads();
  int cb = b << BSHIFT;
  for (int j = t; j < 512; j += 256) { int col = cb + j; if (col < NN) deg[col] = h[j]; }
}

__global__ void k_dn(const int* __restrict__ deg, float* __restrict__ dn) {
  int i = blockIdx.x * blockDim.x + threadIdx.x;
  if (i < NN) { int d = deg[i]; dn[i] = d > 0 ? rsqrtf((float)d) : 0.f; }
}

#define SCAN_CH 1024
__global__ void k_scan_part(const int* __restrict__ deg, int* __restrict__ partials) {
  __shared__ int lds[4];
  int b = blockIdx.x, t = threadIdx.x;
  int base = b * SCAN_CH;
  int s = 0;
  for (int j = 0; j < 4; ++j) { int i = base + t + 256 * j; if (i < NN) s += deg[i]; }
  for (int d = 32; d > 0; d >>= 1) s += __shfl_down(s, d, 64);
  int lane = t & 63, w = t >> 6;
  if (lane == 0) lds[w] = s;
  __syncthreads();
  if (t == 0) partials[b] = lds[0] + lds[1] + lds[2] + lds[3];
}

__global__ void k_scan_partials(int* __restrict__ partials, int nb) {
  __shared__ int lds[2];
  int t = threadIdx.x;  // 128 threads, nb <= 128
  int v = (t < nb) ? partials[t] : 0;
  int lane = t & 63, w = t >> 6;
  int s = v;
  for (int d = 1; d < 64; d <<= 1) { int o = __shfl_up(s, d, 64); if (lane >= d) s += o; }
  if (lane == 63) lds[w] = s;
  __syncthreads();
  int base = (w == 1) ? lds[0] : 0;
  if (t < nb) partials[t] = base + s - v;  // exclusive
}

__global__ void k_scan_final(const int* __restrict__ deg, const int* __restrict__ partials,
                             int* __restrict__ colptr, int* __restrict__ pos) {
  __shared__ int lds[4];
  int b = blockIdx.x, t = threadIdx.x;
  int base = b * SCAN_CH + t * 4;
  int d0 = (base + 0 < NN) ? deg[base + 0] : 0;
  int d1 = (base + 1 < NN) ? deg[base + 1] : 0;
  int d2 = (base + 2 < NN) ? deg[base + 2] : 0;
  int d3 = (base + 3 < NN) ? deg[base + 3] : 0;
  int tot = d0 + d1 + d2 + d3;
  int lane = t & 63, w = t >> 6;
  int s = tot;
  for (int d = 1; d < 64; d <<= 1) { int o = __shfl_up(s, d, 64); if (lane >= d) s += o; }
  if (lane == 63) lds[w] = s;
  __syncthreads();
  int wbase = 0;
  for (int i = 0; i < 4; ++i) wbase += (i < w) ? lds[i] : 0;
  int excl = wbase + s - tot + partials[b];
  int p0 = excl, p1 = p0 + d0, p2 = p1 + d1, p3 = p2 + d2, p4 = p3 + d3;
  if (base + 0 <= NN) colptr[base + 0] = p0;
  if (base + 1 <= NN) colptr[base + 1] = p1;
  if (base + 2 <= NN) colptr[base + 2] = p2;
  if (base + 3 <= NN) colptr[base + 3] = p3;
  if (base + 4 == NN) colptr[NN] = p4;
  if (base + 0 < NN) pos[base + 0] = p0;
  if (base + 1 < NN) pos[base + 1] = p1;
  if (base + 2 < NN) pos[base + 2] = p2;
  if (base + 3 < NN) pos[base + 3] = p3;
}

// Pass 5: final fill from bucketed edges — pos atomics + csr_row writes are L2-local per bucket
__global__ __launch_bounds__(256) void k_fill2(const long long* __restrict__ ebuf,
                                               int* __restrict__ pos, int* __restrict__ csr_row) {
  int e = blockIdx.x * 256 + threadIdx.x;
  if (e < NE) {
    long long pk = ebuf[e];
    int col = (int)(pk >> 32), row = (int)pk;
    int p = atomicAdd(&pos[col], 1);
    csr_row[p] = row;
  }
}

// ---------------- weight prep: transpose to [n][k] bf16, fold BN+bias ----------------
__global__ void k_prep(const float* __restrict__ fc0_W, const float* __restrict__ fc0_b,
                       const float* __restrict__ conv_W, const float* __restrict__ conv_b,
                       const float* __restrict__ bn_gamma, const float* __restrict__ bn_beta,
                       const float* __restrict__ bn_mean, const float* __restrict__ bn_var,
                       const float* __restrict__ clf_W,
                       unsigned short* __restrict__ W0t, unsigned short* __restrict__ Wct,
                       unsigned short* __restrict__ Wclft,
                       float* __restrict__ epia, float* __restrict__ epib) {
  int idx = blockIdx.x * 256 + threadIdx.x;
  if (idx < 131072) {                       // W0t[n*512+k] = fc0_W[k][n]
    int n = idx >> 9, k = idx & 511;
    W0t[idx] = f2b(fc0_W[k * 256 + n]);
  } else if (idx < 262144) {                // Wct[l][n*256+k] = conv_W[l][k][n]
    int j = idx - 131072;
    int l = j >> 16, rem = j & 65535, n = rem >> 8, k = rem & 255;
    Wct[j] = f2b(conv_W[l * 65536 + k * 256 + n]);
  } else if (idx < 262144 + 48 * 256) {     // Wclft[n*256+k], rows 40..47 zero
    int j = idx - 262144;
    int n = j >> 8, k = j & 255;
    Wclft[j] = f2b(n < NOUT ? clf_W[k * NOUT + n] : 0.f);
  } else if (idx < 262144 + 12288 + 768) {  // epilogue constants per BN layer
    int j = idx - 262144 - 12288;           // layer*256 + c
    int layer = j >> 8, c = j & 255;
    float a = bn_gamma[j] * rsqrtf(bn_var[j] + 1e-5f);
    float bias = (layer == 0) ? fc0_b[c] : conv_b[(layer - 1) * 256 + c];
    epia[j] = a;
    epib[j] = bn_beta[j] + (bias - bn_mean[j]) * a;
  }
}

// ---------------- MFMA GEMM: [NN x K] * [K x BN] with fused epilogue ----------------
// EPI 0: y=relu(a*acc+b) -> bf16     EPI 1: +prev residual -> bf16     EPI 2: acc+clf_b -> f32 (col<40)
template <int K, int BN_, bool AF32, int EPI>
__global__ __launch_bounds__(256) void k_gemm(const void* __restrict__ Av,
                                              const unsigned short* __restrict__ Bt,
                                              const float* __restrict__ epia,
                                              const float* __restrict__ epib,
                                              const unsigned short* __restrict__ prev,
                                              const float* __restrict__ clfb,
                                              void* __restrict__ outv) {
  __shared__ unsigned short ldsA[64 * 32];
  __shared__ unsigned short ldsB[BN_ * 32];
  const int t = threadIdx.x;
  const int w = t >> 6, lane = t & 63;
  const int lo = lane & 15, hi = lane >> 4;
  const int m0 = blockIdx.x * 64;
  constexpr int NF = BN_ / 16;
  f32x4 acc[NF];
#pragma unroll
  for (int f = 0; f < NF; ++f) acc[f] = (f32x4){0.f, 0.f, 0.f, 0.f};

  const int arow = t >> 2;       // 0..63
  const int akk = (t & 3) * 8;   // element offset in K-step
  const int rg = m0 + arow;

  for (int k0 = 0; k0 < K; k0 += 32) {
    if (AF32) {
      const float* A = (const float*)Av;
      float4 v0 = {0.f, 0.f, 0.f, 0.f}, v1 = {0.f, 0.f, 0.f, 0.f};
      if (rg < NN) {
        v0 = *(const float4*)(A + (size_t)rg * K + k0 + akk);
        v1 = *(const float4*)(A + (size_t)rg * K + k0 + akk + 4);
      }
      union { unsigned short u[8]; int4 v; } pk;
      pk.u[0] = f2b(v0.x); pk.u[1] = f2b(v0.y); pk.u[2] = f2b(v0.z); pk.u[3] = f2b(v0.w);
      pk.u[4] = f2b(v1.x); pk.u[5] = f2b(v1.y); pk.u[6] = f2b(v1.z); pk.u[7] = f2b(v1.w);
      *(int4*)(void*)swz(ldsA, arow, akk) = pk.v;
    } else {
      const unsigned short* A = (const unsigned short*)Av;
      int4 v = {0, 0, 0, 0};
      if (rg < NN) v = *(const int4*)(A + (size_t)rg * K + k0 + akk);
      *(int4*)(void*)swz(ldsA, arow, akk) = v;
    }
    if (BN_ == 256) {
#pragma unroll
      for (int j = 0; j < 4; ++j) {
        int n = (t >> 2) + 64 * j;
        int4 v = *(const int4*)(Bt + (size_t)n * K + k0 + akk);
        *(int4*)(void*)swz(ldsB, n, akk) = v;
      }
    } else {
      if (t < BN_ * 4) {
        int n = t >> 2;
        int4 v = *(const int4*)(Bt + (size_t)n * K + k0 + akk);
        *(int4*)(void*)swz(ldsB, n, akk) = v;
      }
    }
    __syncthreads();
    bf16x8 af = *(const bf16x8*)(void*)swz(ldsA, w * 16 + lo, hi * 8);
#pragma unroll
    for (int f = 0; f < NF; ++f) {
      bf16x8 bf = *(const bf16x8*)(void*)swz(ldsB, f * 16 + lo, hi * 8);
      acc[f] = __builtin_amdgcn_mfma_f32_16x16x32_bf16(af, bf, acc[f], 0, 0, 0);
    }
    __syncthreads();
  }

  const int rbase = m0 + w * 16 + hi * 4;  // C/D: col=lane&15, row=(lane>>4)*4+reg
  if constexpr (EPI == 2) {
    float* out = (float*)outv;
#pragma unroll
    for (int f = 0; f < NF; ++f) {
      int c = f * 16 + lo;
      if (c >= NOUT) continue;
      float bb = clfb[c];
#pragma unroll
      for (int j = 0; j < 4; ++j) {
        int r = rbase + j;
        if (r < NN) out[(size_t)r * NOUT + c] = acc[f][j] + bb;
      }
    }
  } else {
    unsigned short* out = (unsigned short*)outv;
#pragma unroll
    for (int f = 0; f < NF; ++f) {
      int c = f * 16 + lo;
      float a = epia[c], b = epib[c];
#pragma unroll
      for (int j = 0; j < 4; ++j) {
        int r = rbase + j;
        if (r >= NN) continue;
        float y = fmaxf(a * acc[f][j] + b, 0.f);
        if constexpr (EPI == 1) y += b2f(prev[(size_t)r * HID + c]);
        out[(size_t)r * HID + c] = f2b(y);
      }
    }
  }
}

// ---------------- aggregation: one wave per node, CSR gather, MLP=4 ----------------
__global__ __launch_bounds__(256) void k_agg(const int* __restrict__ colptr,
                                             const int* __restrict__ csr_row,
                                             const float* __restrict__ dn,
                                             const unsigned short* __restrict__ hsrc,
                                             unsigned short* __restrict__ hdst) {
  int w = threadIdx.x >> 6, lane = threadIdx.x & 63;
  int i = blockIdx.x * 4 + w;
  if (i >= NN) return;
  int e0 = colptr[i], e1 = colptr[i + 1];
  float a0 = 0.f, a1 = 0.f, a2 = 0.f, a3 = 0.f;
  int e = e0;
  for (; e + 4 <= e1; e += 4) {
    int r0 = csr_row[e], r1 = csr_row[e + 1], r2 = csr_row[e + 2], r3 = csr_row[e + 3];
    float v0 = dn[r0], v1 = dn[r1], v2 = dn[r2], v3 = dn[r3];
    ushort4 h0 = *(const ushort4*)(hsrc + (size_t)r0 * HID + lane * 4);
    ushort4 h1 = *(const ushort4*)(hsrc + (size_t)r1 * HID + lane * 4);
    ushort4 h2 = *(const ushort4*)(hsrc + (size_t)r2 * HID + lane * 4);
    ushort4 h3 = *(const ushort4*)(hsrc + (size_t)r3 * HID + lane * 4);
    a0 += v0 * b2f(h0.x) + v1 * b2f(h1.x) + v2 * b2f(h2.x) + v3 * b2f(h3.x);
    a1 += v0 * b2f(h0.y) + v1 * b2f(h1.y) + v2 * b2f(h2.y) + v3 * b2f(h3.y);
    a2 += v0 * b2f(h0.z) + v1 * b2f(h1.z) + v2 * b2f(h2.z) + v3 * b2f(h3.z);
    a3 += v0 * b2f(h0.w) + v1 * b2f(h1.w) + v2 * b2f(h2.w) + v3 * b2f(h3.w);
  }
  for (; e < e1; ++e) {
    int r0 = csr_row[e];
    float v0 = dn[r0];
    ushort4 h0 = *(const ushort4*)(hsrc + (size_t)r0 * HID + lane * 4);
    a0 += v0 * b2f(h0.x); a1 += v0 * b2f(h0.y); a2 += v0 * b2f(h0.z); a3 += v0 * b2f(h0.w);
  }
  float dni = dn[i];
  ushort4 o; o.x = f2b(dni * a0); o.y = f2b(dni * a1); o.z = f2b(dni * a2); o.w = f2b(dni * a3);
  *(ushort4*)(hdst + (size_t)i * HID + lane * 4) = o;
}

extern "C" void kernel_launch(void* const* d_in, const int* in_sizes, int n_in,
                              void* d_out, int out_size, void* d_ws, size_t ws_size,
                              hipStream_t stream) {
  const float* x        = (const float*)d_in[0];
  const int*   edge     = (const int*)d_in[1];
  const int*   erow     = edge;
  const int*   ecol     = edge + NE;
  const float* fc0_W    = (const float*)d_in[2];
  const float* fc0_b    = (const float*)d_in[3];
  const float* conv_W   = (const float*)d_in[4];
  const float* conv_b   = (const float*)d_in[5];
  const float* bn_gamma = (const float*)d_in[6];
  const float* bn_beta  = (const float*)d_in[7];
  const float* bn_mean  = (const float*)d_in[8];
  const float* bn_var   = (const float*)d_in[9];
  const float* clf_W    = (const float*)d_in[10];
  const float* clf_b    = (const float*)d_in[11];

  char* p = (char*)d_ws;
  auto alloc = [&](size_t bytes) { char* r = p; p += (bytes + 255) & ~(size_t)255; return r; };
  int*   deg      = (int*)alloc((size_t)NN * 4);
  float* dn       = (float*)alloc((size_t)NN * 4);
  int*   colptr   = (int*)alloc((size_t)(NN + 1) * 4);
  int*   pos      = (int*)alloc((size_t)NN * 4);
  int*   partials = (int*)alloc(1024);
  int*   bcnt     = (int*)alloc(NB * 4);
  int*   bbase    = (int*)alloc(NB * 4);
  int*   cursor   = (int*)alloc(NB * 4);
  int*   csr_row  = (int*)alloc((size_t)NE * 4);
  unsigned short* W0t   = (unsigned short*)alloc((size_t)256 * 512 * 2);
  unsigned short* Wct   = (unsigned short*)alloc((size_t)2 * 256 * 256 * 2);
  unsigned short* Wclft = (unsigned short*)alloc((size_t)48 * 256 * 2);
  float* epia = (float*)alloc(768 * 4);
  float* epib = (float*)alloc(768 * 4);
  unsigned short* h0 = (unsigned short*)alloc((size_t)NN * HID * 2);
  unsigned short* hA = (unsigned short*)alloc((size_t)NN * HID * 2);
  unsigned short* hB = (unsigned short*)alloc((size_t)NN * HID * 2);
  long long* ebuf = (long long*)hA;  // alias: ebuf dead before hA first written

  int nbBlk = (NE + EPB - 1) / EPB;  // 391
  hipMemsetAsync(bcnt, 0, NB * 4, stream);
  k_bhist<<<nbBlk, 256, 0, stream>>>(ecol, bcnt);
  k_bscan<<<1, 256, 0, stream>>>(bcnt, bbase, cursor);
  k_bucket<<<nbBlk, 256, 0, stream>>>(erow, ecol, cursor, ebuf);
  k_subdeg<<<196, 256, 0, stream>>>(ebuf, bbase, bcnt, deg);
  k_dn<<<(NN + 255) / 256, 256, 0, stream>>>(deg, dn);
  int nb = (NN + SCAN_CH - 1) / SCAN_CH;  // 98
  k_scan_part<<<nb, 256, 0, stream>>>(deg, partials);
  k_scan_partials<<<1, 128, 0, stream>>>(partials, nb);
  k_scan_final<<<nb, 256, 0, stream>>>(deg, partials, colptr, pos);
  k_fill2<<<(NE + 255) / 256, 256, 0, stream>>>(ebuf, pos, csr_row);
  k_prep<<<1075, 256, 0, stream>>>(fc0_W, fc0_b, conv_W, conv_b, bn_gamma, bn_beta,
                                   bn_mean, bn_var, clf_W, W0t, Wct, Wclft, epia, epib);

  int gm = (NN + 63) / 64;  // 1563
  // fc0 + BN0 + ReLU -> h0
  k_gemm<KIN, 256, true, 0><<<gm, 256, 0, stream>>>(x, W0t, epia, epib, nullptr, nullptr, h0);
  // layer 0
  k_agg<<<(NN + 3) / 4, 256, 0, stream>>>(colptr, csr_row, dn, h0, hA);
  k_gemm<HID, 256, false, 1><<<gm, 256, 0, stream>>>(hA, Wct, epia + 256, epib + 256, h0, nullptr, hB);
  // layer 1
  k_agg<<<(NN + 3) / 4, 256, 0, stream>>>(colptr, csr_row, dn, hB, hA);
  k_gemm<HID, 256, false, 1><<<gm, 256, 0, stream>>>(hA, Wct + 65536, epia + 512, epib + 512, h0, nullptr, hB);
  // classifier -> f32 out
  k_gemm<HID, 48, false, 2><<<gm, 256, 0, stream>>>(hB, Wclft, nullptr, nullptr, nullptr, clf_b, d_out);
}